// Round 15
// baseline (109.621 us; speedup 1.0000x reference)
//
#include <hip/hip_runtime.h>
#include <hip/hip_bf16.h>
#include <stdint.h>

// SketchConv2d: out = conv2d(x, Weff) + bias, where
// Weff[o,f] = (1/4) * sum_{n,s} sketches[n,f,s] * signed[n,s,o]
// f channel-major flat (c*9 + kh*3 + kw).
//
// B=32, CIN=128, H=W=64, OUT=256, KH=KW=3, H2=W2=62, NSK=4, SDIM=128.
//
// Round 15: m201 8-phase template, exact cadence, sound publish chain.
//  - K = 18 BK=64 tiles (tap-major), 9 iters x 2 tiles; A dbuf 2x32 KB.
//  - Phase: {8 or 4 ds_reads (BEFORE barrier) | stage | [vmcnt(0) @P2/P6]
//    | s_barrier | lgkm0+sched_barrier(0) | setprio1 16 MFMA setprio0
//    | s_barrier}. Stages batched: P0 = odd tile (4 glds), P4 = next even.
//    Every stage is certified by a vmcnt+barrier 2 phases after issue, and
//    every read consumes data published >= 1 phase-pair earlier -> reads
//    can sit before the barrier (skew-drain) with no cross-wave race.
//  - B resident in LDS (96 KB, r13-verified layout/pointers).

#define BATCH 32
#define CIN   128
#define HH    64
#define WW    64
#define OUTC  256
#define H2    62
#define W2    62
#define A_TILE 32768                  // 256 o x 64 k x 2B per BK=64 tile
#define WS_A_BYTES (18 * A_TILE)      // 576 KB
#define BROWB 16384                   // 64 j * 256 B per x-row
#define AMAXOFF (17 * A_TILE)

typedef __bf16 bf16x8 __attribute__((ext_vector_type(8)));
typedef float  f32x4  __attribute__((ext_vector_type(4)));

typedef unsigned int u32_as1 __attribute__((address_space(1)));
typedef unsigned int u32_as3 __attribute__((address_space(3)));

__device__ __forceinline__ void async_copy16(const void* g, void* l) {
  __builtin_amdgcn_global_load_lds((const u32_as1*)g, (u32_as3*)l, 16, 0, 0);
}

// ---------------------------------------------------------------------------
// Kernel 1: Weff -> 18 fragment-linear BK=64 tile images in ws.
// T = tap*2 + (c>>6); within tile: og=o>>4, ks=(c>>5)&1, ke=c&31,
// l = ((ke>>3)<<4)|(o&15), e = ke&7:
// byte = T*32768 + og*2048 + ks*1024 + l*16 + e*2.
// ---------------------------------------------------------------------------
#define FPB 4
__global__ __launch_bounds__(256) void weff_kernel(
    const float* __restrict__ sketches,   // (4, 1152, 128)
    const float* __restrict__ sgn,        // (4, 128, 256)
    char* __restrict__ wsA)
{
  __shared__ alignas(16) float sk[512 * FPB];
  const int f0 = blockIdx.x * FPB;
  const int t  = threadIdx.x;

  for (int k = 0; k < (512 * FPB) / 256; ++k) {
    int idx = t + k * 256;
    int fi  = idx >> 9;
    int ns  = idx & 511;
    int n   = ns >> 7;
    int s   = ns & 127;
    sk[ns * FPB + fi] = sketches[(n * 1152 + f0 + fi) * 128 + s];
  }
  __syncthreads();

  const int o = t;
  float acc0 = 0.f, acc1 = 0.f, acc2 = 0.f, acc3 = 0.f;
#pragma unroll 8
  for (int ns = 0; ns < 512; ++ns) {
    float sg = sgn[ns * 256 + o];
    f32x4 skv = *(const f32x4*)(&sk[ns * FPB]);
    acc0 += sg * skv[0];
    acc1 += sg * skv[1];
    acc2 += sg * skv[2];
    acc3 += sg * skv[3];
  }

  float accs[FPB] = {acc0, acc1, acc2, acc3};
#pragma unroll
  for (int fi = 0; fi < FPB; ++fi) {
    int f   = f0 + fi;
    int c   = f / 9;
    int tap = f - c * 9;
    int T   = tap * 2 + (c >> 6);
    int cc  = c & 63;
    int ks  = cc >> 5;
    int ke  = cc & 31;
    int l   = ((ke >> 3) << 4) | (o & 15);
    int e   = ke & 7;
    uint32_t byteoff = (uint32_t)T * A_TILE + (uint32_t)(o >> 4) * 2048
                     + (uint32_t)ks * 1024 + (uint32_t)l * 16 + (uint32_t)e * 2;
    *(__hip_bfloat16*)(wsA + byteoff) = __float2bfloat16(accs[fi] * 0.25f);
  }
}

// ---------------------------------------------------------------------------
// Kernel 2: implicit-GEMM conv, 8-phase pipelined K-loop.
// Block (b, ig): 256 o x 256 e (4 i-rows x 64 j), 8 waves (512 thr).
// wave: wm = w>>2 (o-half of 128 rows), we = w&3 (i-row).
// ---------------------------------------------------------------------------
__global__ __launch_bounds__(512, 2) void conv_kernel(
    const float* __restrict__ x,
    const char*  __restrict__ wA,
    const float* __restrict__ bias,
    float* __restrict__ out)
{
  __shared__ alignas(16) char lds[2 * A_TILE + 6 * BROWB];  // 64 + 96 KB
  char* ldsA = lds;
  char* ldsB = lds + 2 * A_TILE;

  const int bid = blockIdx.x;
  const int swz = (bid & 7) * 64 + (bid >> 3);    // 512 = 8*64, bijective
  const int b   = swz >> 4;
  const int ig  = swz & 15;
  const int i0  = ig * 4;

  const int t    = threadIdx.x;
  const int lane = t & 63;
  const int w    = t >> 6;       // 0..7
  const int wm   = w >> 2;       // o-half (128 rows)
  const int we   = w & 3;        // i-row within group

  // stage one full 32 KB tile (both o-halves): 4 glds, per-thread t*16
#define STG4(SOFF) do {                                                    \
    uint32_t so_ = (SOFF);                                                 \
    uint32_t ds_ = (so_ <= (uint32_t)AMAXOFF) ? (so_ & (uint32_t)A_TILE)   \
                                              : 0u;                        \
    if (so_ > (uint32_t)AMAXOFF) so_ = 0;                                  \
    const char* s_ = wA + so_ + t * 16;                                    \
    char* d_ = ldsA + ds_ + t * 16;                                        \
    async_copy16(s_,          d_);                                         \
    async_copy16(s_ + 8192,   d_ + 8192);                                  \
    async_copy16(s_ + 16384,  d_ + 16384);                                 \
    async_copy16(s_ + 24576,  d_ + 24576);                                 \
  } while (0)

  STG4(0u);   // prologue: tile 0 into slot 0

  // ---- stage B once: x[b, :, i0..i0+5 (row-clamped), :] -> [r][j][c] swz
  {
    const int j  = t & 63;
    const int cq = t >> 6;                         // 8 groups of 16 channels
    const uint32_t swb = (uint32_t)((j & 7) << 4);
#pragma unroll
    for (int r = 0; r < 6; ++r) {
      int xrow = i0 + r; if (xrow > 63) xrow = 63;
      const float* xr = x + (((size_t)(b * CIN + cq * 16)) * HH + xrow) * WW + j;
      char* lrow = ldsB + r * BROWB + j * 256;
#pragma unroll
      for (int g = 0; g < 2; ++g) {
        bf16x8 pk;
#pragma unroll
        for (int cc = 0; cc < 8; ++cc)
          pk[cc] = (__bf16)xr[(size_t)(g * 8 + cc) * (HH * WW)];
        uint32_t c0b = (uint32_t)(cq * 32 + g * 16);
        *(bf16x8*)(lrow + (c0b ^ swb)) = pk;
      }
    }
  }

  f32x4 acc[8][4];
  const f32x4 zf = {0.f, 0.f, 0.f, 0.f};
#pragma unroll
  for (int mi = 0; mi < 8; ++mi)
#pragma unroll
    for (int ni = 0; ni < 4; ++ni)
      acc[mi][ni] = zf;

  // ---- per-lane LDS read bases
  const int ln15  = lane & 15;
  const int khi16 = (lane >> 4) << 4;
  const char* pAw = ldsA + wm * 16384 + lane * 16;   // + slot*32768 + mi*2048 + ks*1024

#define MKB(COL, PAR) (ldsB + we * BROWB + (COL) * 256                     \
    + (uint32_t)(((((PAR) * 64) | khi16) ^ (((COL) & 7) << 4))))
  const char* pB00 = MKB(ln15 + 0, 0); const char* pB01 = MKB(ln15 + 0, 1);
  const char* pB10 = MKB(ln15 + 1, 0); const char* pB11 = MKB(ln15 + 1, 1);
  const char* pB20 = MKB(ln15 + 2, 0); const char* pB21 = MKB(ln15 + 2, 1);
  const int c30 = (48 + ln15 + 0 > 63) ? 63 : 48 + ln15 + 0;
  const int c31 = (48 + ln15 + 1 > 63) ? 63 : 48 + ln15 + 1;
  const int c32 = (48 + ln15 + 2 > 63) ? 63 : 48 + ln15 + 2;
  const char* pC00 = MKB(c30, 0); const char* pC01 = MKB(c30, 1);
  const char* pC10 = MKB(c31, 0); const char* pC11 = MKB(c31, 1);
  const char* pC20 = MKB(c32, 0); const char* pC21 = MKB(c32, 1);
#undef MKB

  __syncthreads();   // drains tile-0 glds (vmcnt0) + all B ds_writes

  bf16x8 a0_, a1_, a2_, a3_, b0_, b1_, b2_, b3_;
  uint32_t tb = 0;   // byte offset of this iter's even tile

#define MFMA_ __builtin_amdgcn_mfma_f32_16x16x32_bf16
#define VM0   asm volatile("s_waitcnt vmcnt(0)" ::: "memory")
#define LGKM0 asm volatile("s_waitcnt lgkmcnt(0)" ::: "memory")
#define SB0   __builtin_amdgcn_sched_barrier(0)

#define RD_A(SLOT, MIG, KS) do {                                           \
    a0_ = *(const bf16x8*)(pAw + (SLOT)*A_TILE + ((MIG)*4+0)*2048 + (KS)*1024); \
    a1_ = *(const bf16x8*)(pAw + (SLOT)*A_TILE + ((MIG)*4+1)*2048 + (KS)*1024); \
    a2_ = *(const bf16x8*)(pAw + (SLOT)*A_TILE + ((MIG)*4+2)*2048 + (KS)*1024); \
    a3_ = *(const bf16x8*)(pAw + (SLOT)*A_TILE + ((MIG)*4+3)*2048 + (KS)*1024); \
  } while (0)

#define RD_B(KW, KS, H) do {                                               \
    b0_ = *(const bf16x8*)(pB##KW##KS + (H) * 128);                        \
    b1_ = *(const bf16x8*)(pB##KW##KS + (H) * 128 + 4096);                 \
    b2_ = *(const bf16x8*)(pB##KW##KS + (H) * 128 + 8192);                 \
    b3_ = *(const bf16x8*)(pC##KW##KS + (H) * 128);                        \
  } while (0)

#define TAIL(MIG) do {                                                     \
    __builtin_amdgcn_s_barrier();                                          \
    LGKM0; SB0;                                                            \
    __builtin_amdgcn_s_setprio(1);                                         \
    acc[(MIG)*4+0][0] = MFMA_(a0_, b0_, acc[(MIG)*4+0][0], 0, 0, 0);       \
    acc[(MIG)*4+0][1] = MFMA_(a0_, b1_, acc[(MIG)*4+0][1], 0, 0, 0);       \
    acc[(MIG)*4+0][2] = MFMA_(a0_, b2_, acc[(MIG)*4+0][2], 0, 0, 0);       \
    acc[(MIG)*4+0][3] = MFMA_(a0_, b3_, acc[(MIG)*4+0][3], 0, 0, 0);       \
    acc[(MIG)*4+1][0] = MFMA_(a1_, b0_, acc[(MIG)*4+1][0], 0, 0, 0);       \
    acc[(MIG)*4+1][1] = MFMA_(a1_, b1_, acc[(MIG)*4+1][1], 0, 0, 0);       \
    acc[(MIG)*4+1][2] = MFMA_(a1_, b2_, acc[(MIG)*4+1][2], 0, 0, 0);       \
    acc[(MIG)*4+1][3] = MFMA_(a1_, b3_, acc[(MIG)*4+1][3], 0, 0, 0);       \
    acc[(MIG)*4+2][0] = MFMA_(a2_, b0_, acc[(MIG)*4+2][0], 0, 0, 0);       \
    acc[(MIG)*4+2][1] = MFMA_(a2_, b1_, acc[(MIG)*4+2][1], 0, 0, 0);       \
    acc[(MIG)*4+2][2] = MFMA_(a2_, b2_, acc[(MIG)*4+2][2], 0, 0, 0);       \
    acc[(MIG)*4+2][3] = MFMA_(a2_, b3_, acc[(MIG)*4+2][3], 0, 0, 0);       \
    acc[(MIG)*4+3][0] = MFMA_(a3_, b0_, acc[(MIG)*4+3][0], 0, 0, 0);       \
    acc[(MIG)*4+3][1] = MFMA_(a3_, b1_, acc[(MIG)*4+3][1], 0, 0, 0);       \
    acc[(MIG)*4+3][2] = MFMA_(a3_, b2_, acc[(MIG)*4+3][2], 0, 0, 0);       \
    acc[(MIG)*4+3][3] = MFMA_(a3_, b3_, acc[(MIG)*4+3][3], 0, 0, 0);       \
    __builtin_amdgcn_s_setprio(0);                                         \
    __builtin_amdgcn_s_barrier();                                          \
  } while (0)

  // one iter = tiles (even: slot0, H=0) then (odd: slot1, H=1), 8 phases.
  // stages: P0 = odd tile (4 glds), P4 = next even tile (dummy past T17).
  // vmcnt(0) at P2 (publishes odd, issued P0) and P6 (next even, issued P4)
  // -> every read consumes data published >= 1 phase-pair earlier.
#define ITER(KW) do {                                                      \
    /* P0 */ STG4(tb + A_TILE);                                            \
             RD_A(0, 0, 0); RD_B(KW, 0, 0);            TAIL(0);            \
    /* P1 */ RD_A(0, 1, 0);                            TAIL(1);            \
    /* P2 */ RD_A(0, 0, 1); RD_B(KW, 1, 0); VM0;       TAIL(0);            \
    /* P3 */ RD_A(0, 1, 1);                            TAIL(1);            \
    /* P4 */ STG4(tb + 2 * A_TILE);                                        \
             RD_A(1, 0, 0); RD_B(KW, 0, 1);            TAIL(0);            \
    /* P5 */ RD_A(1, 1, 0);                            TAIL(1);            \
    /* P6 */ RD_A(1, 0, 1); RD_B(KW, 1, 1); VM0;       TAIL(0);            \
    /* P7 */ RD_A(1, 1, 1);                            TAIL(1);            \
    tb += 2 * A_TILE;                                                      \
  } while (0)

#pragma unroll 1
  for (int kh = 0; kh < 3; ++kh) {
    ITER(0);
    ITER(1);
    ITER(2);
    if (kh < 2) {
      pB00 += BROWB; pB01 += BROWB; pB10 += BROWB; pB11 += BROWB;
      pB20 += BROWB; pB21 += BROWB; pC00 += BROWB; pC01 += BROWB;
      pC10 += BROWB; pC11 += BROWB; pC20 += BROWB; pC21 += BROWB;
    }
  }

#undef ITER
#undef TAIL
#undef RD_B
#undef RD_A
#undef SB0
#undef LGKM0
#undef VM0
#undef MFMA_
#undef STG4

  // ---- epilogue: D[m][n]: m=(lane>>4)*4+reg, n=lane&15
  const int jn   = ln15;
  const int g4   = lane >> 4;
  const int irow = i0 + we;
  if (irow < H2) {
#pragma unroll
    for (int mi = 0; mi < 8; ++mi) {
#pragma unroll
      for (int ni = 0; ni < 4; ++ni) {
        const int jj = (ni << 4) + jn;
        if (jj < W2) {
#pragma unroll
          for (int rr = 0; rr < 4; ++rr) {
            const int o = (wm << 7) + (mi << 4) + (g4 << 2) + rr;
            out[(((size_t)b * OUTC + o) * H2 + irow) * W2 + jj] =
                acc[mi][ni][rr] + bias[o];
          }
        }
      }
    }
  }
}

extern "C" void kernel_launch(void* const* d_in, const int* in_sizes, int n_in,
                              void* d_out, int out_size, void* d_ws, size_t ws_size,
                              hipStream_t stream) {
  const float* x        = (const float*)d_in[0];
  const float* sketches = (const float*)d_in[1];
  const float* sgn      = (const float*)d_in[2];
  const float* bias     = (const float*)d_in[3];
  float* out            = (float*)d_out;
  char* wsA             = (char*)d_ws;

  if (ws_size < (size_t)WS_A_BYTES) return;  // need 576 KB scratch

  weff_kernel<<<1152 / FPB, 256, 0, stream>>>(sketches, sgn, wsA);
  conv_kernel<<<BATCH * 16, 512, 0, stream>>>(x, wsA, bias, out);
}